// Round 1
// baseline (94340.625 us; speedup 1.0000x reference)
//
#include <hip/hip_runtime.h>
#include <math.h>

#define BB 128
#define TT 512
#define HH 1024
#define VV 1024
#define II 512
#define H3 3072

// workspace float offsets
#define U_OFF   524288          // E1 is [0, V*I)
#define C_OFF   524800
#define Hh_OFF  525312
#define HID_OFF 656384
#define Z_OFF   721920
#define ACC_OFF 852992
#define CNT_OFF 852996

__device__ __forceinline__ void gbar(int* cnt, int& epoch) {
  __syncthreads();
  if (threadIdx.x == 0) {
    epoch += (int)gridDim.x;
    __hip_atomic_fetch_add(cnt, 1, __ATOMIC_RELEASE, __HIP_MEMORY_SCOPE_AGENT);
    while (__hip_atomic_load(cnt, __ATOMIC_RELAXED, __HIP_MEMORY_SCOPE_AGENT) < epoch) {
      __builtin_amdgcn_s_sleep(1);
    }
    __builtin_amdgcn_fence(__ATOMIC_ACQUIRE, "agent");
  }
  __syncthreads();
}

// ---------------------------------------------------------------------------
// Kernel 1: precompute E1 = embed_obs @ W1_oe^T, u = W1_ve @ Wv, c = W1_ve @ bv + b1,
//           init h = broadcast(h_init), zero loss accumulators + barrier counter.
// ---------------------------------------------------------------------------
__global__ __launch_bounds__(256, 1) void k_pre(
    const float* __restrict__ embed, const float* __restrict__ W1,
    const float* __restrict__ Wv, const float* __restrict__ bv,
    const float* __restrict__ b1, const float* __restrict__ hinit,
    float* __restrict__ ws) {
  const int bid = blockIdx.x, tid = threadIdx.x;
  float* E1 = ws;
  float* u = ws + U_OFF;
  float* c = ws + C_OFF;
  float* h = ws + Hh_OFF;

  // E1 tile: grid = 16x16 tiles of [64 v x 32 i]
  {
    const int vt = bid >> 4, it = bid & 15;
    const int il = tid & 31;   // i lane 0..31
    const int vg = tid >> 5;   // v group 0..7
    const int i = it * 32 + il;
    const float4* wr = reinterpret_cast<const float4*>(W1 + (size_t)i * H3 + HH);
    float acc[8];
    #pragma unroll
    for (int q = 0; q < 8; ++q) acc[q] = 0.f;
    const int vbase = vt * 64 + vg * 8;
    for (int k = 0; k < HH / 4; ++k) {
      const float4 w4 = wr[k];
      #pragma unroll
      for (int q = 0; q < 8; ++q) {
        const float4 e4 =
            reinterpret_cast<const float4*>(embed + (size_t)(vbase + q) * HH)[k];
        acc[q] += e4.x * w4.x + e4.y * w4.y + e4.z * w4.z + e4.w * w4.w;
      }
    }
    #pragma unroll
    for (int q = 0; q < 8; ++q) E1[(size_t)(vbase + q) * II + i] = acc[q];
  }

  if (bid == 0) {
    // u[i], c[i]
    for (int i = tid; i < II; i += 256) {
      const float* w = W1 + (size_t)i * H3 + 2 * HH;
      float au = 0.f, ac = 0.f;
      for (int k = 0; k < HH; ++k) {
        const float wv = w[k];
        au = fmaf(wv, Wv[k], au);
        ac = fmaf(wv, bv[k], ac);
      }
      u[i] = au;
      c[i] = ac + b1[i];
    }
  } else if (bid == 1) {
    for (int idx = tid; idx < BB * HH; idx += 256) h[idx] = hinit[idx & (HH - 1)];
  } else if (bid == 2 && tid == 0) {
    ws[ACC_OFF] = 0.f;
    ws[ACC_OFF + 1] = 0.f;
    *reinterpret_cast<int*>(ws + CNT_OFF) = 0;
  }
}

// ---------------------------------------------------------------------------
// Kernel 2: the sequential recurrence. 256 blocks x 256 threads, persistent,
// custom device-scope barrier. 3 phases per step:
//   A: hid_t = relu(h_t @ W1_h^T + a_t)  [16b x 16i tiles]
//      (+ pred_{t-1} = h_t @ W_out^T     [16b x 32v tiles])
//   B: z_t = sig*. (h_t @ W_rec^T) + (1-sig)*s_t + b_rec   [16b x 32j tiles]
//   C: h_{t+1} = leaky(LN(z_t))  [one block per row]
// ---------------------------------------------------------------------------
__global__ __launch_bounds__(256, 1) void k_seq(
    const int* __restrict__ obs, const float* __restrict__ vel,
    const float* __restrict__ W1, const float* __restrict__ W2,
    const float* __restrict__ b2, const float* __restrict__ Wrec,
    const float* __restrict__ Wout, const float* __restrict__ embed,
    const float* __restrict__ Wv, const float* __restrict__ bv,
    const float* __restrict__ brec, float* __restrict__ ws,
    float* __restrict__ out_pred) {
  const int bid = blockIdx.x, tid = threadIdx.x;
  const int bg = bid >> 5;  // 0..7 : 16-row batch group
  const int jt = bid & 31;  // 0..31: column tile
  float* E1 = ws;
  float* u = ws + U_OFF;
  float* c = ws + C_OFF;
  float* h = ws + Hh_OFF;
  float* hid = ws + HID_OFF;
  float* z = ws + Z_OFF;
  int* cnt = reinterpret_cast<int*>(ws + CNT_OFF);
  int epoch = 0;

  __shared__ float redA[4], redB[4], mv2[2];

  const int b = (bg << 4) + (tid & 15);
  const int q16 = tid >> 4;  // 0..15

  for (int t = 0; t <= TT; ++t) {
    // ---------------- Phase A ----------------
    {
      const float4* hrow = reinterpret_cast<const float4*>(h + (size_t)b * HH);
      if (t < TT) {
        const int i = (jt << 4) + q16;
        const float4* wr = reinterpret_cast<const float4*>(W1 + (size_t)i * H3);
        float acc = 0.f;
        #pragma unroll 4
        for (int k = 0; k < HH / 4; ++k) {
          const float4 hv = hrow[k], wv = wr[k];
          acc = fmaf(hv.x, wv.x, acc);
          acc = fmaf(hv.y, wv.y, acc);
          acc = fmaf(hv.z, wv.z, acc);
          acc = fmaf(hv.w, wv.w, acc);
        }
        const int o = obs[b * TT + t];
        const float vvel = vel[b * TT + t];
        const float pre = acc + E1[(size_t)o * II + i] + vvel * u[i] + c[i];
        hid[b * II + i] = pre > 0.f ? pre : 0.f;
      }
      if (t > 0) {
        const int v0 = (jt << 5) + q16;
        const float4* w0 = reinterpret_cast<const float4*>(Wout + (size_t)v0 * HH);
        const float4* w1 =
            reinterpret_cast<const float4*>(Wout + (size_t)(v0 + 16) * HH);
        float a0 = 0.f, a1 = 0.f;
        #pragma unroll 4
        for (int k = 0; k < HH / 4; ++k) {
          const float4 hv = hrow[k];
          const float4 x0 = w0[k], x1 = w1[k];
          a0 = fmaf(hv.x, x0.x, a0); a0 = fmaf(hv.y, x0.y, a0);
          a0 = fmaf(hv.z, x0.z, a0); a0 = fmaf(hv.w, x0.w, a0);
          a1 = fmaf(hv.x, x1.x, a1); a1 = fmaf(hv.y, x1.y, a1);
          a1 = fmaf(hv.z, x1.z, a1); a1 = fmaf(hv.w, x1.w, a1);
        }
        float* orow = out_pred + ((size_t)b * TT + (t - 1)) * VV;
        orow[v0] = a0;
        orow[v0 + 16] = a1;
      }
    }
    gbar(cnt, epoch);
    if (t == TT) break;

    // ---------------- Phase B ----------------
    {
      const int j0 = (jt << 5) + q16;
      const int j1 = j0 + 16;
      const float4* hrow = reinterpret_cast<const float4*>(h + (size_t)b * HH);
      const float4* y0 = reinterpret_cast<const float4*>(Wrec + (size_t)j0 * HH);
      const float4* y1 = reinterpret_cast<const float4*>(Wrec + (size_t)j1 * HH);
      float r0 = 0.f, r1 = 0.f;
      #pragma unroll 4
      for (int k = 0; k < HH / 4; ++k) {
        const float4 hv = hrow[k];
        const float4 a4 = y0[k], c4 = y1[k];
        r0 = fmaf(hv.x, a4.x, r0); r0 = fmaf(hv.y, a4.y, r0);
        r0 = fmaf(hv.z, a4.z, r0); r0 = fmaf(hv.w, a4.w, r0);
        r1 = fmaf(hv.x, c4.x, r1); r1 = fmaf(hv.y, c4.y, r1);
        r1 = fmaf(hv.z, c4.z, r1); r1 = fmaf(hv.w, c4.w, r1);
      }
      const float4* dr = reinterpret_cast<const float4*>(hid + (size_t)b * II);
      const float4* v20 = reinterpret_cast<const float4*>(W2 + (size_t)j0 * II);
      const float4* v21 = reinterpret_cast<const float4*>(W2 + (size_t)j1 * II);
      float g0 = 0.f, g1 = 0.f;
      #pragma unroll 4
      for (int k = 0; k < II / 4; ++k) {
        const float4 dv = dr[k];
        const float4 a4 = v20[k], c4 = v21[k];
        g0 = fmaf(dv.x, a4.x, g0); g0 = fmaf(dv.y, a4.y, g0);
        g0 = fmaf(dv.z, a4.z, g0); g0 = fmaf(dv.w, a4.w, g0);
        g1 = fmaf(dv.x, c4.x, g1); g1 = fmaf(dv.y, c4.y, g1);
        g1 = fmaf(dv.z, c4.z, g1); g1 = fmaf(dv.w, c4.w, g1);
      }
      g0 = 1.f / (1.f + expf(-(g0 + b2[j0])));
      g1 = 1.f / (1.f + expf(-(g1 + b2[j1])));
      const int o = obs[b * TT + t];
      const float vvel = vel[b * TT + t];
      const float s0 = embed[(size_t)o * HH + j0] + vvel * Wv[j0] + bv[j0];
      const float s1 = embed[(size_t)o * HH + j1] + vvel * Wv[j1] + bv[j1];
      z[b * HH + j0] = g0 * r0 + (1.f - g0) * s0 + brec[j0];
      z[b * HH + j1] = g1 * r1 + (1.f - g1) * s1 + brec[j1];
    }
    gbar(cnt, epoch);

    // ---------------- Phase C: LayerNorm + leaky relu ----------------
    if (bid < BB) {
      const int row = bid;
      const float4 z4 = reinterpret_cast<const float4*>(z + (size_t)row * HH)[tid];
      float s1 = z4.x + z4.y + z4.z + z4.w;
      float s2 = z4.x * z4.x + z4.y * z4.y + z4.z * z4.z + z4.w * z4.w;
      #pragma unroll
      for (int off = 32; off >= 1; off >>= 1) {
        s1 += __shfl_down(s1, off, 64);
        s2 += __shfl_down(s2, off, 64);
      }
      const int wid = tid >> 6, lane = tid & 63;
      if (lane == 0) { redA[wid] = s1; redB[wid] = s2; }
      __syncthreads();
      if (tid == 0) {
        const float S1 = redA[0] + redA[1] + redA[2] + redA[3];
        const float S2 = redB[0] + redB[1] + redB[2] + redB[3];
        const float mu = S1 * (1.f / HH);
        const float var = S2 * (1.f / HH) - mu * mu;
        mv2[0] = mu;
        mv2[1] = rsqrtf(var + 1e-5f);
      }
      __syncthreads();
      const float mu = mv2[0], rs = mv2[1];
      float4 o4;
      float v;
      v = (z4.x - mu) * rs; o4.x = v >= 0.f ? v : 0.01f * v;
      v = (z4.y - mu) * rs; o4.y = v >= 0.f ? v : 0.01f * v;
      v = (z4.z - mu) * rs; o4.z = v >= 0.f ? v : 0.01f * v;
      v = (z4.w - mu) * rs; o4.w = v >= 0.f ? v : 0.01f * v;
      reinterpret_cast<float4*>(h + (size_t)row * HH)[tid] = o4;
    }
    gbar(cnt, epoch);
  }
}

// ---------------------------------------------------------------------------
// Kernel 3: mask + masked NLL accumulation (per-row logsumexp over V=1024)
// ---------------------------------------------------------------------------
__global__ __launch_bounds__(256) void k_loss(
    const float* __restrict__ preds, const int* __restrict__ tgt,
    const int* __restrict__ lens, float* __restrict__ mask_out,
    float* __restrict__ acc) {
  const int tid = threadIdx.x;
  const int wid = tid >> 6, lane = tid & 63;
  __shared__ float ln_[4], ld_[4];
  float npart = 0.f, dpart = 0.f;
  const int nwaves = gridDim.x * 4;
  for (int row = blockIdx.x * 4 + wid; row < BB * TT; row += nwaves) {
    const int bb = row >> 9;
    const int t = row & (TT - 1);
    const int L = lens[bb];
    const float mv = (t >= L - 1) ? 1.f : 0.f;
    if (lane == 0) mask_out[row] = mv;
    if (mv > 0.f) {
      const float4* pr = reinterpret_cast<const float4*>(preds + (size_t)row * VV);
      const float4 p0 = pr[lane], p1 = pr[lane + 64];
      const float4 p2 = pr[lane + 128], p3 = pr[lane + 192];
      float m = fmaxf(fmaxf(fmaxf(p0.x, p0.y), fmaxf(p0.z, p0.w)),
                      fmaxf(fmaxf(p1.x, p1.y), fmaxf(p1.z, p1.w)));
      m = fmaxf(m, fmaxf(fmaxf(fmaxf(p2.x, p2.y), fmaxf(p2.z, p2.w)),
                         fmaxf(fmaxf(p3.x, p3.y), fmaxf(p3.z, p3.w))));
      #pragma unroll
      for (int off = 32; off >= 1; off >>= 1) m = fmaxf(m, __shfl_xor(m, off, 64));
      float s = expf(p0.x - m) + expf(p0.y - m) + expf(p0.z - m) + expf(p0.w - m) +
                expf(p1.x - m) + expf(p1.y - m) + expf(p1.z - m) + expf(p1.w - m) +
                expf(p2.x - m) + expf(p2.y - m) + expf(p2.z - m) + expf(p2.w - m) +
                expf(p3.x - m) + expf(p3.y - m) + expf(p3.z - m) + expf(p3.w - m);
      #pragma unroll
      for (int off = 32; off >= 1; off >>= 1) s += __shfl_xor(s, off, 64);
      if (lane == 0) {
        const float lt = preds[(size_t)row * VV + tgt[row]];
        npart += (m + logf(s)) - lt;
        dpart += 1.f;
      }
    }
  }
  if (lane == 0) { ln_[wid] = npart; ld_[wid] = dpart; }
  __syncthreads();
  if (tid == 0) {
    atomicAdd(acc + 0, ln_[0] + ln_[1] + ln_[2] + ln_[3]);
    atomicAdd(acc + 1, ld_[0] + ld_[1] + ld_[2] + ld_[3]);
  }
}

__global__ void k_fin(const float* __restrict__ acc, float* __restrict__ out) {
  out[0] = acc[0] / (acc[1] + 1e-8f);
}

// ---------------------------------------------------------------------------
extern "C" void kernel_launch(void* const* d_in, const int* in_sizes, int n_in,
                              void* d_out, int out_size, void* d_ws, size_t ws_size,
                              hipStream_t stream) {
  const int* obs = (const int*)d_in[0];
  const float* vel = (const float*)d_in[1];
  const int* tgt = (const int*)d_in[2];
  const int* lens = (const int*)d_in[3];
  const float* embed = (const float*)d_in[4];
  const float* Wv = (const float*)d_in[5];
  const float* bv = (const float*)d_in[6];
  const float* W1 = (const float*)d_in[7];
  const float* b1 = (const float*)d_in[8];
  const float* W2 = (const float*)d_in[9];
  const float* b2 = (const float*)d_in[10];
  const float* Wrec = (const float*)d_in[11];
  const float* Wout = (const float*)d_in[12];
  const float* hinit = (const float*)d_in[13];
  const float* brec = (const float*)d_in[14];
  float* out = (float*)d_out;
  float* ws = (float*)d_ws;

  k_pre<<<256, 256, 0, stream>>>(embed, W1, Wv, bv, b1, hinit, ws);
  k_seq<<<256, 256, 0, stream>>>(obs, vel, W1, W2, b2, Wrec, Wout, embed, Wv, bv,
                                 brec, ws, out + 1);
  k_loss<<<1024, 256, 0, stream>>>(out + 1, tgt, lens,
                                   out + 1 + (size_t)BB * TT * VV, ws + ACC_OFF);
  k_fin<<<1, 1, 0, stream>>>(ws + ACC_OFF, out);
}

// Round 5
// 36743.335 us; speedup vs baseline: 2.5676x; 2.5676x over previous
//
#include <hip/hip_runtime.h>
#include <math.h>

#define BB 128
#define TT 512
#define HH 1024
#define VV 1024
#define II 512
#define H3 3072

#define NG 8            // groups (one per XCD, heuristically)
#define GB 32           // blocks per group
#define ROWS 16         // batch rows per group
#define CPB 80          // unified cols per block (2560/32)

// ws float offsets
#define E1_OFF 0
#define U_OFF   524288
#define C_OFF   524800
#define GS_OFF  525312          // per-group scratch, stride GSZ floats
#define GSZ     65536
#define G_HID   0               // [16][512]
#define G_R     8192            // [16][1024]
#define G_Z     24576           // [2][16][1024]
#define G_STATS 57344           // [2][16] float2
#define BAR_OFF (GS_OFF + NG * GSZ)   // 8 counters spaced 64 floats (256 B)

__device__ __forceinline__ void gbar(int* cnt, int& epoch) {
  __syncthreads();
  if (threadIdx.x == 0) {
    epoch += GB;
    __hip_atomic_fetch_add(cnt, 1, __ATOMIC_RELEASE, __HIP_MEMORY_SCOPE_AGENT);
    while (__hip_atomic_load(cnt, __ATOMIC_RELAXED, __HIP_MEMORY_SCOPE_AGENT) < epoch) {
      __builtin_amdgcn_s_sleep(1);
    }
    __builtin_amdgcn_fence(__ATOMIC_ACQUIRE, "agent");
  }
  __syncthreads();
}

// ---------------------------------------------------------------------------
// Kernel 1: E1 = embed_obs @ W1_oe^T ; u = W1_ve @ Wv ; c = W1_ve @ bv + b1 ;
//           zero stats + barrier counters.
// ---------------------------------------------------------------------------
__global__ __launch_bounds__(256, 1) void k_pre(
    const float* __restrict__ embed, const float* __restrict__ W1,
    const float* __restrict__ Wv, const float* __restrict__ bv,
    const float* __restrict__ b1, float* __restrict__ ws) {
  const int bid = blockIdx.x, tid = threadIdx.x;
  float* E1 = ws + E1_OFF;
  float* u = ws + U_OFF;
  float* c = ws + C_OFF;

  // E1 tile: 16x16 tiles of [64 v x 32 i]
  {
    const int vt = bid >> 4, it = bid & 15;
    const int il = tid & 31;
    const int vg = tid >> 5;
    const int i = it * 32 + il;
    const float4* wr = reinterpret_cast<const float4*>(W1 + (size_t)i * H3 + HH);
    float acc[8];
    #pragma unroll
    for (int q = 0; q < 8; ++q) acc[q] = 0.f;
    const int vbase = vt * 64 + vg * 8;
    for (int k = 0; k < HH / 4; ++k) {
      const float4 w4 = wr[k];
      #pragma unroll
      for (int q = 0; q < 8; ++q) {
        const float4 e4 =
            reinterpret_cast<const float4*>(embed + (size_t)(vbase + q) * HH)[k];
        acc[q] += e4.x * w4.x + e4.y * w4.y + e4.z * w4.z + e4.w * w4.w;
      }
    }
    #pragma unroll
    for (int q = 0; q < 8; ++q) E1[(size_t)(vbase + q) * II + i] = acc[q];
  }

  if (bid == 0) {
    for (int i = tid; i < II; i += 256) {
      const float* w = W1 + (size_t)i * H3 + 2 * HH;
      float au = 0.f, ac = 0.f;
      for (int k = 0; k < HH; ++k) {
        const float wv = w[k];
        au = fmaf(wv, Wv[k], au);
        ac = fmaf(wv, bv[k], ac);
      }
      u[i] = au;
      c[i] = ac + b1[i];
    }
  } else if (bid == 1) {
    // zero barrier counters (8 x 64 floats) and all group stats (8 x 64 floats)
    for (int idx = tid; idx < NG * 64; idx += 256) ws[BAR_OFF + idx] = 0.f;
    for (int g = 0; g < NG; ++g)
      for (int idx = tid; idx < 64; idx += 256)
        ws[GS_OFF + (size_t)g * GSZ + G_STATS + idx] = 0.f;
  }
}

// ---------------------------------------------------------------------------
// Kernel 2: sequential recurrence. 8 groups x 32 blocks x 512 threads.
// Per step: stage h=leaky(LN(z_prev)) into LDS (k-major float4);
//   P1: [hid | r | pred] = h @ [W1_h | Wrec | Wout]^T   (16 x 2560 x 1024)
//   gbar ; P2: sigma = sig(hid@W2^T+b2); z = sig*r+(1-sig)*s+brec ; stats ; gbar
// ---------------------------------------------------------------------------
__global__ __launch_bounds__(512, 2) void k_seq(
    const int* __restrict__ obs, const float* __restrict__ vel,
    const float* __restrict__ W1, const float* __restrict__ W2,
    const float* __restrict__ b2, const float* __restrict__ Wrec,
    const float* __restrict__ Wout, const float* __restrict__ embed,
    const float* __restrict__ Wv, const float* __restrict__ bv,
    const float* __restrict__ brec, const float* __restrict__ hinit,
    float* __restrict__ ws, float* __restrict__ preds) {
  const int bid = blockIdx.x, tid = threadIdx.x;
  const int g = bid & 7, gi = bid >> 3;
  float* grp = ws + GS_OFF + (size_t)g * GSZ;
  float* hid = grp + G_HID;
  float* rbuf = grp + G_R;
  float* zbuf = grp + G_Z;
  float2* stats = reinterpret_cast<float2*>(grp + G_STATS);
  int* cnt = reinterpret_cast<int*>(ws + BAR_OFF + g * 64);
  int epoch = 0;

  float* E1 = ws + E1_OFF;
  const float* u = ws + U_OFF;
  const float* cbias = ws + C_OFF;

  __shared__ float4 lds4[4096];  // 64 KB: P1 h-tile [256 k4][16 b]; P2 hid [128 k4][16 b]
  float* sred = reinterpret_cast<float*>(lds4 + 2048);  // P2 stats scratch (32 floats)

  const int b = tid & 15;
  const int cl = tid >> 4;  // 0..31
  const int brow = g * ROWS + b;

  const int s_row = tid & 15;
  const int s_k4 = tid >> 4;  // 0..31

  for (int t = 0; t <= TT; ++t) {
    // ---- stage h (LN applied on the fly) ----
    if (t == 0) {
      const float4* hi4 = reinterpret_cast<const float4*>(hinit);
      #pragma unroll
      for (int q = 0; q < 8; ++q) {
        const int k4 = s_k4 + 32 * q;
        lds4[(k4 << 4) + s_row] = hi4[k4];
      }
    } else {
      const int par = (t - 1) & 1;
      const float2 st = stats[par * 16 + s_row];
      const float mu = st.x * (1.f / HH);
      const float var = st.y * (1.f / HH) - mu * mu;
      const float rs = rsqrtf(var + 1e-5f);
      const float4* zr =
          reinterpret_cast<const float4*>(zbuf + par * 16384 + s_row * HH);
      #pragma unroll
      for (int q = 0; q < 8; ++q) {
        const int k4 = s_k4 + 32 * q;
        float4 z4 = zr[k4];
        float4 h4;
        float v;
        v = (z4.x - mu) * rs; h4.x = v >= 0.f ? v : 0.01f * v;
        v = (z4.y - mu) * rs; h4.y = v >= 0.f ? v : 0.01f * v;
        v = (z4.z - mu) * rs; h4.z = v >= 0.f ? v : 0.01f * v;
        v = (z4.w - mu) * rs; h4.w = v >= 0.f ? v : 0.01f * v;
        lds4[(k4 << 4) + s_row] = h4;
      }
    }
    __syncthreads();

    const int o_b = (t < TT) ? obs[brow * TT + t] : 0;
    const float vel_b = (t < TT) ? vel[brow * TT + t] : 0.f;

    // ---- P1: unified GEMM ----
    {
      const int cb = gi * CPB;
      const int c0 = cb + cl, c1 = cb + 32 + cl, c2 = cb + 64 + cl;
      auto wptr = [&](int c) -> const float4* {
        if (c < 512) return reinterpret_cast<const float4*>(W1 + (size_t)c * H3);
        if (c < 1536)
          return reinterpret_cast<const float4*>(Wrec + (size_t)(c - 512) * HH);
        return reinterpret_cast<const float4*>(Wout + (size_t)(c - 1536) * HH);
      };
      float t0, t1, t2 = 0.f;
      const bool has3 = (cl < 16);
      if (has3) {
        const float4 *w0 = wptr(c0), *w1 = wptr(c1), *w2 = wptr(c2);
        float4 a0 = {0, 0, 0, 0}, a1 = {0, 0, 0, 0}, a2 = {0, 0, 0, 0};
        #pragma unroll 4
        for (int k4 = 0; k4 < 256; ++k4) {
          const float4 h4 = lds4[(k4 << 4) + b];
          const float4 x0 = w0[k4], x1 = w1[k4], x2 = w2[k4];
          a0.x = fmaf(h4.x, x0.x, a0.x); a0.y = fmaf(h4.y, x0.y, a0.y);
          a0.z = fmaf(h4.z, x0.z, a0.z); a0.w = fmaf(h4.w, x0.w, a0.w);
          a1.x = fmaf(h4.x, x1.x, a1.x); a1.y = fmaf(h4.y, x1.y, a1.y);
          a1.z = fmaf(h4.z, x1.z, a1.z); a1.w = fmaf(h4.w, x1.w, a1.w);
          a2.x = fmaf(h4.x, x2.x, a2.x); a2.y = fmaf(h4.y, x2.y, a2.y);
          a2.z = fmaf(h4.z, x2.z, a2.z); a2.w = fmaf(h4.w, x2.w, a2.w);
        }
        t0 = (a0.x + a0.y) + (a0.z + a0.w);
        t1 = (a1.x + a1.y) + (a1.z + a1.w);
        t2 = (a2.x + a2.y) + (a2.z + a2.w);
      } else {
        const float4 *w0 = wptr(c0), *w1 = wptr(c1);
        float4 a0 = {0, 0, 0, 0}, a1 = {0, 0, 0, 0};
        #pragma unroll 4
        for (int k4 = 0; k4 < 256; ++k4) {
          const float4 h4 = lds4[(k4 << 4) + b];
          const float4 x0 = w0[k4], x1 = w1[k4];
          a0.x = fmaf(h4.x, x0.x, a0.x); a0.y = fmaf(h4.y, x0.y, a0.y);
          a0.z = fmaf(h4.z, x0.z, a0.z); a0.w = fmaf(h4.w, x0.w, a0.w);
          a1.x = fmaf(h4.x, x1.x, a1.x); a1.y = fmaf(h4.y, x1.y, a1.y);
          a1.z = fmaf(h4.z, x1.z, a1.z); a1.w = fmaf(h4.w, x1.w, a1.w);
        }
        t0 = (a0.x + a0.y) + (a0.z + a0.w);
        t1 = (a1.x + a1.y) + (a1.z + a1.w);
      }
      auto emit = [&](int c, float tot) {
        if (c < 512) {
          if (t < TT) {
            const float pre = tot + E1[(size_t)o_b * II + c] + vel_b * u[c] + cbias[c];
            hid[b * II + c] = pre > 0.f ? pre : 0.f;
          }
        } else if (c < 1536) {
          if (t < TT) rbuf[b * HH + (c - 512)] = tot;
        } else {
          if (t >= 1) preds[((size_t)brow * TT + (t - 1)) * VV + (c - 1536)] = tot;
        }
      };
      emit(c0, t0);
      emit(c1, t1);
      if (has3) emit(c2, t2);
    }
    gbar(cnt, epoch);
    if (t == TT) break;

    // ---- stage hid into LDS (k-major) + zero stats scratch ----
    {
      const float4* hr = reinterpret_cast<const float4*>(hid + s_row * II);
      #pragma unroll
      for (int q = 0; q < 4; ++q) {
        const int k4 = s_k4 + 32 * q;
        lds4[(k4 << 4) + s_row] = hr[k4];
      }
      if (tid < 32) sred[tid] = 0.f;
    }
    __syncthreads();

    // ---- P2: gate + z + LN stats ----
    {
      const int j = gi * 32 + cl;
      const float4* w2r = reinterpret_cast<const float4*>(W2 + (size_t)j * II);
      float4 a = {0, 0, 0, 0};
      #pragma unroll 4
      for (int k4 = 0; k4 < 128; ++k4) {
        const float4 h4 = lds4[(k4 << 4) + b];
        const float4 x = w2r[k4];
        a.x = fmaf(h4.x, x.x, a.x); a.y = fmaf(h4.y, x.y, a.y);
        a.z = fmaf(h4.z, x.z, a.z); a.w = fmaf(h4.w, x.w, a.w);
      }
      const float tot = (a.x + a.y) + (a.z + a.w) + b2[j];
      const float sg = 1.f / (1.f + expf(-tot));
      const float rv = rbuf[b * HH + j];
      const float s_in = embed[(size_t)o_b * HH + j] + vel_b * Wv[j] + bv[j];
      const float zv = sg * rv + (1.f - sg) * s_in + brec[j];
      const int par = t & 1;
      zbuf[par * 16384 + b * HH + j] = zv;
      atomicAdd(&sred[b], zv);
      atomicAdd(&sred[16 + b], zv * zv);
      __syncthreads();
      if (tid < 16) {
        atomicAdd(&stats[par * 16 + tid].x, sred[tid]);
        atomicAdd(&stats[par * 16 + tid].y, sred[16 + tid]);
      }
      if (gi == 0 && tid < 16) {
        stats[(1 - par) * 16 + tid].x = 0.f;
        stats[(1 - par) * 16 + tid].y = 0.f;
      }
    }
    gbar(cnt, epoch);
  }
}

// ---------------------------------------------------------------------------
// Kernel 3: mask + masked NLL (per-row logsumexp over V=1024)
// ---------------------------------------------------------------------------
__global__ __launch_bounds__(256) void k_loss(
    const float* __restrict__ preds, const int* __restrict__ tgt,
    const int* __restrict__ lens, float* __restrict__ mask_out,
    float* __restrict__ acc) {
  const int tid = threadIdx.x;
  const int wid = tid >> 6, lane = tid & 63;
  __shared__ float ln_[4], ld_[4];
  float npart = 0.f, dpart = 0.f;
  const int nwaves = gridDim.x * 4;
  for (int row = blockIdx.x * 4 + wid; row < BB * TT; row += nwaves) {
    const int bb = row >> 9;
    const int t = row & (TT - 1);
    const int L = lens[bb];
    const float mv = (t >= L - 1) ? 1.f : 0.f;
    if (lane == 0) mask_out[row] = mv;
    if (mv > 0.f) {
      const float4* pr = reinterpret_cast<const float4*>(preds + (size_t)row * VV);
      const float4 p0 = pr[lane], p1 = pr[lane + 64];
      const float4 p2 = pr[lane + 128], p3 = pr[lane + 192];
      float m = fmaxf(fmaxf(fmaxf(p0.x, p0.y), fmaxf(p0.z, p0.w)),
                      fmaxf(fmaxf(p1.x, p1.y), fmaxf(p1.z, p1.w)));
      m = fmaxf(m, fmaxf(fmaxf(fmaxf(p2.x, p2.y), fmaxf(p2.z, p2.w)),
                         fmaxf(fmaxf(p3.x, p3.y), fmaxf(p3.z, p3.w))));
      #pragma unroll
      for (int off = 32; off >= 1; off >>= 1) m = fmaxf(m, __shfl_xor(m, off, 64));
      float s = expf(p0.x - m) + expf(p0.y - m) + expf(p0.z - m) + expf(p0.w - m) +
                expf(p1.x - m) + expf(p1.y - m) + expf(p1.z - m) + expf(p1.w - m) +
                expf(p2.x - m) + expf(p2.y - m) + expf(p2.z - m) + expf(p2.w - m) +
                expf(p3.x - m) + expf(p3.y - m) + expf(p3.z - m) + expf(p3.w - m);
      #pragma unroll
      for (int off = 32; off >= 1; off >>= 1) s += __shfl_xor(s, off, 64);
      if (lane == 0) {
        const float lt = preds[(size_t)row * VV + tgt[row]];
        npart += (m + logf(s)) - lt;
        dpart += 1.f;
      }
    }
  }
  if (lane == 0) { ln_[wid] = npart; ld_[wid] = dpart; }
  __syncthreads();
  if (tid == 0) {
    atomicAdd(acc + 0, ln_[0] + ln_[1] + ln_[2] + ln_[3]);
    atomicAdd(acc + 1, ld_[0] + ld_[1] + ld_[2] + ld_[3]);
  }
}

__global__ void k_zero(float* __restrict__ acc) {
  acc[0] = 0.f;
  acc[1] = 0.f;
}

__global__ void k_fin(const float* __restrict__ acc, float* __restrict__ out) {
  out[0] = acc[0] / (acc[1] + 1e-8f);
}

// ---------------------------------------------------------------------------
extern "C" void kernel_launch(void* const* d_in, const int* in_sizes, int n_in,
                              void* d_out, int out_size, void* d_ws, size_t ws_size,
                              hipStream_t stream) {
  const int* obs = (const int*)d_in[0];
  const float* vel = (const float*)d_in[1];
  const int* tgt = (const int*)d_in[2];
  const int* lens = (const int*)d_in[3];
  const float* embed = (const float*)d_in[4];
  const float* Wv = (const float*)d_in[5];
  const float* bv = (const float*)d_in[6];
  const float* W1 = (const float*)d_in[7];
  const float* b1 = (const float*)d_in[8];
  const float* W2 = (const float*)d_in[9];
  const float* b2 = (const float*)d_in[10];
  const float* Wrec = (const float*)d_in[11];
  const float* Wout = (const float*)d_in[12];
  const float* hinit = (const float*)d_in[13];
  const float* brec = (const float*)d_in[14];
  float* out = (float*)d_out;
  float* ws = (float*)d_ws;
  float* acc = ws + BAR_OFF + NG * 64;  // 2-float loss accumulator

  k_zero<<<1, 1, 0, stream>>>(acc);
  k_pre<<<256, 256, 0, stream>>>(embed, W1, Wv, bv, b1, ws);
  k_seq<<<256, 512, 0, stream>>>(obs, vel, W1, W2, b2, Wrec, Wout, embed, Wv, bv,
                                 brec, hinit, ws, out + 1);
  k_loss<<<1024, 256, 0, stream>>>(out + 1, tgt, lens,
                                   out + 1 + (size_t)BB * TT * VV, acc);
  k_fin<<<1, 1, 0, stream>>>(acc, out);
}